// Round 15
// baseline (456.995 us; speedup 1.0000x reference)
//
#include <hip/hip_runtime.h>

#define F_IN  128
#define F_HID 64
#define F_OUT 40
#define BSZ   256          // nodes per bucket
#define BSH   8            // log2(BSZ)
#define NB_MAX 512
#define CAP   12288        // bucket region capacity (mean 8163, sigma ~90)

typedef __attribute__((ext_vector_type(8))) short v8s;      // 8 bf16 (4 VGPRs)
typedef __attribute__((ext_vector_type(4))) float v4f;      // 4 fp32 acc
typedef __attribute__((ext_vector_type(4))) unsigned u4v;   // native uint4

// pack two floats as bf16 pair (round-to-nearest-even): low16 = a, high16 = b
static __device__ __forceinline__ unsigned pack_bf16(float a, float b) {
    unsigned ua = __float_as_uint(a);
    unsigned ub = __float_as_uint(b);
    ua = (ua + 0x7fffu + ((ua >> 16) & 1u)) >> 16;
    ub = (ub + 0x7fffu + ((ub >> 16) & 1u)) & 0xffff0000u;
    return ua | ub;
}
static __device__ __forceinline__ float bf_lo(unsigned u) { return __uint_as_float(u << 16); }
static __device__ __forceinline__ float bf_hi(unsigned u) { return __uint_as_float(u & 0xffff0000u); }

// ---------------- partition edges into destination buckets ----------------
__global__ void k_partition(const int* __restrict__ row, const int* __restrict__ col,
                            int E, int nb, int* __restrict__ gcur,
                            unsigned* __restrict__ bbuf) {
    __shared__ int hist[NB_MAX];
    __shared__ int cur[NB_MAX];
    int t = threadIdx.x;
    for (int i = t; i < nb; i += 256) hist[i] = 0;
    __syncthreads();
    int chunk = (E + gridDim.x - 1) / gridDim.x;
    int e0 = blockIdx.x * chunk;
    int e1 = min(E, e0 + chunk);
    for (int e = e0 + t; e < e1; e += 256)
        atomicAdd(&hist[col[e] >> BSH], 1);
    __syncthreads();
    for (int i = t; i < nb; i += 256)
        cur[i] = i * CAP + atomicAdd(&gcur[i], hist[i]);
    __syncthreads();
    for (int e = e0 + t; e < e1; e += 256) {
        int c = col[e];
        int b = c >> BSH;
        int pos = atomicAdd(&cur[b], 1);
        if (pos < (b + 1) * CAP)
            bbuf[pos] = ((unsigned)row[e] << BSH) | (unsigned)(c & (BSZ - 1));
    }
}

// ---------------- per-bucket counting sort -> bucket-relative CSR ----------------
__global__ void __launch_bounds__(1024)
k_csr(const unsigned* __restrict__ bbuf, const int* __restrict__ gcur,
      int* __restrict__ beg, int* __restrict__ deg, float* __restrict__ dinv,
      int* __restrict__ srow, int n) {
    __shared__ unsigned pay[CAP];   // 48 KB
    __shared__ int cnt[BSZ];
    __shared__ int cur[BSZ];
    int b = blockIdx.x, t = threadIdx.x;
    int nE = min(gcur[b], CAP);
    int base = b * CAP;
    if (t < BSZ) cnt[t] = 0;
    __syncthreads();
    for (int i = t; i < nE; i += 1024) {
        unsigned u = bbuf[base + i];
        pay[i] = u;
        atomicAdd(&cnt[u & (BSZ - 1)], 1);
    }
    __syncthreads();
    if (t < BSZ) cur[t] = cnt[t];
    __syncthreads();
    for (int off = 1; off < BSZ; off <<= 1) {
        int add = (t < BSZ && t >= off) ? cur[t - off] : 0;
        __syncthreads();
        if (t < BSZ) cur[t] += add;
        __syncthreads();
    }
    int node0 = b * BSZ;
    if (t < BSZ) {
        int ex = cur[t] - cnt[t];
        int node = node0 + t;
        if (node < n) {
            beg[node] = base + ex;
            deg[node] = cnt[t];
            dinv[node] = rsqrtf((float)cnt[t] + 1.0f);
        }
        cur[t] = ex;
    }
    __syncthreads();
    for (int i = t; i < nE; i += 1024) {
        unsigned u = pay[i];
        int pos = atomicAdd(&cur[u & (BSZ - 1)], 1);
        srow[base + pos] = (int)(u >> BSH);
    }
}

// ---------------- W1 fragments + zero dummy rows + zero gcur (runs first) ----------------
__global__ void k_w1frag(const float* __restrict__ W1, unsigned* __restrict__ w1f,
                         unsigned* __restrict__ h1b, unsigned* __restrict__ h2b,
                         int* __restrict__ gcur, int n) {
    int gid = blockIdx.x * 256 + threadIdx.x;
    if (gid < 32) h1b[(size_t)n * 32 + gid] = 0u;        // dummy zero row (layer 1)
    if (gid < 32) h2b[(size_t)n * 32 + gid] = 0u;        // dummy zero row (layer 2)
    if (gid < NB_MAX) gcur[gid] = 0;
    if (gid >= 16 * 64) return;
    int f = gid >> 6, l = gid & 63;
    int j0 = f >> 2, ks = f & 3;
    int col = 16 * j0 + (l & 15);
    int kb = ks * 32 + ((l >> 4) << 3);
#pragma unroll
    for (int d = 0; d < 4; ++d) {
        float a = W1[(kb + 2 * d) * F_HID + col];
        float b = W1[(kb + 2 * d + 1) * F_HID + col];
        w1f[(size_t)gid * 4 + d] = pack_bf16(a, b);
    }
}

// ---------------- layer 1 linear via MFMA: h1b = bf16( dinv * (x @ W1) ) ----------------
__global__ void k_lin1(const float* __restrict__ x, const unsigned* __restrict__ w1f,
                       const float* __restrict__ dinv, unsigned* __restrict__ h1b, int n) {
    int t = threadIdx.x;
    int l = t & 63, w = t >> 6;
    int node0 = blockIdx.x * 64 + w * 16;
    int arow = min(node0 + (l & 15), n - 1);   // clamped A-row (safe OOB)
    const u4v* wf4 = (const u4v*)w1f;
    v8s bf[16];
#pragma unroll
    for (int f = 0; f < 16; ++f) {
        u4v u = wf4[f * 64 + l];
        bf[f] = *(v8s*)&u;
    }
    v8s af[4];
#pragma unroll
    for (int ks = 0; ks < 4; ++ks) {
        int kb = ks * 32 + ((l >> 4) << 3);
        const float4* xp = (const float4*)&x[(size_t)arow * F_IN + kb];
        float4 x0 = xp[0], x1 = xp[1];
        u4v uu = { pack_bf16(x0.x, x0.y), pack_bf16(x0.z, x0.w),
                   pack_bf16(x1.x, x1.y), pack_bf16(x1.z, x1.w) };
        af[ks] = *(v8s*)&uu;
    }
#pragma unroll
    for (int j0 = 0; j0 < 4; ++j0) {
        v4f acc = {0.f, 0.f, 0.f, 0.f};
#pragma unroll
        for (int ks = 0; ks < 4; ++ks)
            acc = __builtin_amdgcn_mfma_f32_16x16x32_bf16(af[ks], bf[j0 * 4 + ks], acc, 0, 0, 0);
#pragma unroll
        for (int i = 0; i < 4; ++i) {
            int node = node0 + ((l >> 4) << 2) + i;
            float s = acc[i] * dinv[min(node, n - 1)];
            float pr = __shfl_xor(s, 1);
            if (!(l & 1) && node < n)
                h1b[(size_t)node * 32 + 8 * j0 + ((l & 15) >> 1)] = pack_bf16(s, pr);
        }
    }
}

// gathers: out-of-range lanes carry the dummy row index (n), whose row is zero.
#define ISS(tq, rv, i, u) { int rr = __shfl(rv, (i) * 8 + g); u = tq[(size_t)rr * 8 + c]; }
#define ACC(u, p0,p1,p2,p3,p4,p5,p6,p7) { \
    p0 += bf_lo(u.x); p1 += bf_hi(u.x); p2 += bf_lo(u.y); p3 += bf_hi(u.y); \
    p4 += bf_lo(u.z); p5 += bf_hi(u.z); p6 += bf_lo(u.w); p7 += bf_hi(u.w); }
#define RED(p) { p += __shfl_xor(p, 8); p += __shfl_xor(p, 16); p += __shfl_xor(p, 32); }

// ---------------- layer-1 aggregation (2 nodes/wave, 8 lines in flight) + relu + W2 GEMM ----------------
__global__ void k_agg1(const u4v* __restrict__ h1q, const int* __restrict__ beg,
                       const int* __restrict__ deg, const int* __restrict__ srow,
                       const float* __restrict__ dinv, const float* __restrict__ b1,
                       const float* __restrict__ W2, unsigned* __restrict__ h2b, int n) {
    __shared__ float W2s[F_HID * F_OUT];  // 10 KB
    __shared__ float b1s[F_HID];
    __shared__ float zrow[8][F_HID];      // 2 KB
    int t = threadIdx.x;
    for (int i = t; i < F_HID * F_OUT; i += 256) W2s[i] = W2[i];
    if (t < F_HID) b1s[t] = b1[t];
    __syncthreads();
    int lane = t & 63, w = t >> 6;
    int g = lane >> 3, c = lane & 7;
    int nA = blockIdx.x * 8 + w * 2;
    if (nA >= n) return;
    int nB = nA + 1;
    bool hasB = nB < n;
    int bgA = beg[nA], cntA = deg[nA];
    int bgB = hasB ? beg[nB] : 0, cntB = hasB ? deg[nB] : 0;
    float a0=0,a1=0,a2=0,a3=0,a4=0,a5=0,a6=0,a7=0;
    float b0=0,b1_=0,b2_=0,b3=0,b4=0,b5=0,b6=0,b7=0;
    int cmax = max(cntA, cntB);
    for (int e0 = 0; e0 < cmax; e0 += 64) {
        int rA = (lane < cntA - e0) ? srow[bgA + e0 + lane] : n;
        int rB = (lane < cntB - e0) ? srow[bgB + e0 + lane] : n;
        int iters = (min(cmax - e0, 64) + 7) >> 3;
        u4v uA0, uA1, uA2, uA3, uB0, uB1, uB2, uB3;
        ISS(h1q, rA, 0, uA0) ISS(h1q, rB, 0, uB0)
        ISS(h1q, rA, 1, uA1) ISS(h1q, rB, 1, uB1)
        ISS(h1q, rA, 2, uA2) ISS(h1q, rB, 2, uB2)
        ISS(h1q, rA, 3, uA3) ISS(h1q, rB, 3, uB3)
        ACC(uA0, a0,a1,a2,a3,a4,a5,a6,a7) ACC(uB0, b0,b1_,b2_,b3,b4,b5,b6,b7)
        ACC(uA1, a0,a1,a2,a3,a4,a5,a6,a7) ACC(uB1, b0,b1_,b2_,b3,b4,b5,b6,b7)
        ACC(uA2, a0,a1,a2,a3,a4,a5,a6,a7) ACC(uB2, b0,b1_,b2_,b3,b4,b5,b6,b7)
        ACC(uA3, a0,a1,a2,a3,a4,a5,a6,a7) ACC(uB3, b0,b1_,b2_,b3,b4,b5,b6,b7)
        if (iters > 4) {
            ISS(h1q, rA, 4, uA0) ISS(h1q, rB, 4, uB0)
            if (iters > 5) { ISS(h1q, rA, 5, uA1) ISS(h1q, rB, 5, uB1) }
            if (iters > 6) { ISS(h1q, rA, 6, uA2) ISS(h1q, rB, 6, uB2) }
            if (iters > 7) { ISS(h1q, rA, 7, uA3) ISS(h1q, rB, 7, uB3) }
            ACC(uA0, a0,a1,a2,a3,a4,a5,a6,a7) ACC(uB0, b0,b1_,b2_,b3,b4,b5,b6,b7)
            if (iters > 5) { ACC(uA1, a0,a1,a2,a3,a4,a5,a6,a7) ACC(uB1, b0,b1_,b2_,b3,b4,b5,b6,b7) }
            if (iters > 6) { ACC(uA2, a0,a1,a2,a3,a4,a5,a6,a7) ACC(uB2, b0,b1_,b2_,b3,b4,b5,b6,b7) }
            if (iters > 7) { ACC(uA3, a0,a1,a2,a3,a4,a5,a6,a7) ACC(uB3, b0,b1_,b2_,b3,b4,b5,b6,b7) }
        }
    }
    RED(a0) RED(a1) RED(a2) RED(a3) RED(a4) RED(a5) RED(a6) RED(a7)
    RED(b0) RED(b1_) RED(b2_) RED(b3) RED(b4) RED(b5) RED(b6) RED(b7)
    if (g == 0) {               // node A: self-loop + relu -> zrow[2w]
        u4v us = h1q[(size_t)nA * 8 + c];
        float dv = dinv[nA];
        float z;
        z = fmaf(a0 + bf_lo(us.x), dv, b1s[8*c+0]); zrow[2*w][8*c+0] = z > 0.f ? z : 0.f;
        z = fmaf(a1 + bf_hi(us.x), dv, b1s[8*c+1]); zrow[2*w][8*c+1] = z > 0.f ? z : 0.f;
        z = fmaf(a2 + bf_lo(us.y), dv, b1s[8*c+2]); zrow[2*w][8*c+2] = z > 0.f ? z : 0.f;
        z = fmaf(a3 + bf_hi(us.y), dv, b1s[8*c+3]); zrow[2*w][8*c+3] = z > 0.f ? z : 0.f;
        z = fmaf(a4 + bf_lo(us.z), dv, b1s[8*c+4]); zrow[2*w][8*c+4] = z > 0.f ? z : 0.f;
        z = fmaf(a5 + bf_hi(us.z), dv, b1s[8*c+5]); zrow[2*w][8*c+5] = z > 0.f ? z : 0.f;
        z = fmaf(a6 + bf_lo(us.w), dv, b1s[8*c+6]); zrow[2*w][8*c+6] = z > 0.f ? z : 0.f;
        z = fmaf(a7 + bf_hi(us.w), dv, b1s[8*c+7]); zrow[2*w][8*c+7] = z > 0.f ? z : 0.f;
    } else if (g == 1 && hasB) {  // node B: self-loop + relu -> zrow[2w+1]
        u4v us = h1q[(size_t)nB * 8 + c];
        float dv = dinv[nB];
        float z;
        z = fmaf(b0  + bf_lo(us.x), dv, b1s[8*c+0]); zrow[2*w+1][8*c+0] = z > 0.f ? z : 0.f;
        z = fmaf(b1_ + bf_hi(us.x), dv, b1s[8*c+1]); zrow[2*w+1][8*c+1] = z > 0.f ? z : 0.f;
        z = fmaf(b2_ + bf_lo(us.y), dv, b1s[8*c+2]); zrow[2*w+1][8*c+2] = z > 0.f ? z : 0.f;
        z = fmaf(b3  + bf_hi(us.y), dv, b1s[8*c+3]); zrow[2*w+1][8*c+3] = z > 0.f ? z : 0.f;
        z = fmaf(b4  + bf_lo(us.z), dv, b1s[8*c+4]); zrow[2*w+1][8*c+4] = z > 0.f ? z : 0.f;
        z = fmaf(b5  + bf_hi(us.z), dv, b1s[8*c+5]); zrow[2*w+1][8*c+5] = z > 0.f ? z : 0.f;
        z = fmaf(b6  + bf_lo(us.w), dv, b1s[8*c+6]); zrow[2*w+1][8*c+6] = z > 0.f ? z : 0.f;
        z = fmaf(b7  + bf_hi(us.w), dv, b1s[8*c+7]); zrow[2*w+1][8*c+7] = z > 0.f ? z : 0.f;
    }
    // same-wave DS write->read (in-order DS pipe); two W2 dots per wave
    float sA = 0.f, sB = 0.f;
    if (lane < F_OUT) {
#pragma unroll
        for (int k = 0; k < F_HID; ++k) {
            sA = fmaf(zrow[2*w][k],     W2s[k * F_OUT + lane], sA);
            sB = fmaf(zrow[2*w+1][k],   W2s[k * F_OUT + lane], sB);
        }
        sA *= dinv[nA];
        sB *= hasB ? dinv[nB] : 0.f;
    }
    float pA = __shfl_xor(sA, 1);
    float pB = __shfl_xor(sB, 1);
    if (lane < F_OUT && (lane & 1) == 0) {
        h2b[(size_t)nA * 32 + (lane >> 1)] = pack_bf16(sA, pA);
        if (hasB) h2b[(size_t)nB * 32 + (lane >> 1)] = pack_bf16(sB, pB);
    }
}

// ---------------- layer-2 aggregation (2 nodes/wave) + bias + fused log_softmax ----------------
__global__ void k_agg2(const u4v* __restrict__ h2q, const int* __restrict__ beg,
                       const int* __restrict__ deg, const int* __restrict__ srow,
                       const float* __restrict__ dinv, const float* __restrict__ b2,
                       float* __restrict__ out, int n) {
    int t = threadIdx.x, lane = t & 63, w = t >> 6;
    int g = lane >> 3, c = lane & 7;
    int nA = blockIdx.x * 8 + w * 2;
    if (nA >= n) return;
    int nB = nA + 1;
    bool hasB = nB < n;
    int bgA = beg[nA], cntA = deg[nA];
    int bgB = hasB ? beg[nB] : 0, cntB = hasB ? deg[nB] : 0;
    float a0=0,a1=0,a2=0,a3=0,a4=0,a5=0,a6=0,a7=0;
    float b0=0,b1_=0,b2_=0,b3=0,b4=0,b5=0,b6=0,b7=0;
    int cmax = max(cntA, cntB);
    for (int e0 = 0; e0 < cmax; e0 += 64) {
        int rA = (lane < cntA - e0) ? srow[bgA + e0 + lane] : n;
        int rB = (lane < cntB - e0) ? srow[bgB + e0 + lane] : n;
        int iters = (min(cmax - e0, 64) + 7) >> 3;
        u4v uA0, uA1, uA2, uA3, uB0, uB1, uB2, uB3;
        ISS(h2q, rA, 0, uA0) ISS(h2q, rB, 0, uB0)
        ISS(h2q, rA, 1, uA1) ISS(h2q, rB, 1, uB1)
        ISS(h2q, rA, 2, uA2) ISS(h2q, rB, 2, uB2)
        ISS(h2q, rA, 3, uA3) ISS(h2q, rB, 3, uB3)
        ACC(uA0, a0,a1,a2,a3,a4,a5,a6,a7) ACC(uB0, b0,b1_,b2_,b3,b4,b5,b6,b7)
        ACC(uA1, a0,a1,a2,a3,a4,a5,a6,a7) ACC(uB1, b0,b1_,b2_,b3,b4,b5,b6,b7)
        ACC(uA2, a0,a1,a2,a3,a4,a5,a6,a7) ACC(uB2, b0,b1_,b2_,b3,b4,b5,b6,b7)
        ACC(uA3, a0,a1,a2,a3,a4,a5,a6,a7) ACC(uB3, b0,b1_,b2_,b3,b4,b5,b6,b7)
        if (iters > 4) {
            ISS(h2q, rA, 4, uA0) ISS(h2q, rB, 4, uB0)
            if (iters > 5) { ISS(h2q, rA, 5, uA1) ISS(h2q, rB, 5, uB1) }
            if (iters > 6) { ISS(h2q, rA, 6, uA2) ISS(h2q, rB, 6, uB2) }
            if (iters > 7) { ISS(h2q, rA, 7, uA3) ISS(h2q, rB, 7, uB3) }
            ACC(uA0, a0,a1,a2,a3,a4,a5,a6,a7) ACC(uB0, b0,b1_,b2_,b3,b4,b5,b6,b7)
            if (iters > 5) { ACC(uA1, a0,a1,a2,a3,a4,a5,a6,a7) ACC(uB1, b0,b1_,b2_,b3,b4,b5,b6,b7) }
            if (iters > 6) { ACC(uA2, a0,a1,a2,a3,a4,a5,a6,a7) ACC(uB2, b0,b1_,b2_,b3,b4,b5,b6,b7) }
            if (iters > 7) { ACC(uA3, a0,a1,a2,a3,a4,a5,a6,a7) ACC(uB3, b0,b1_,b2_,b3,b4,b5,b6,b7) }
        }
    }
    RED(a0) RED(a1) RED(a2) RED(a3) RED(a4) RED(a5) RED(a6) RED(a7)
    RED(b0) RED(b1_) RED(b2_) RED(b3) RED(b4) RED(b5) RED(b6) RED(b7)
    // lanes 0-31 finish node A, lanes 32-63 finish node B (each 8-lane c-group redundant)
    bool isB = g >= 4;
    int nd = isB ? nB : nA;
    bool nodeOK = !isB || hasB;
    bool act = (c < 5) && nodeOK;
    float v0=-1e30f,v1=-1e30f,v2=-1e30f,v3=-1e30f,v4=-1e30f,v5=-1e30f,v6=-1e30f,v7=-1e30f;
    if (act) {
        float dv = dinv[nd];
        u4v us = h2q[(size_t)nd * 8 + c];   // self-loop
        float e0 = isB ? b0  : a0, e1 = isB ? b1_ : a1;
        float e2 = isB ? b2_ : a2, e3 = isB ? b3  : a3;
        float e4 = isB ? b4  : a4, e5 = isB ? b5  : a5;
        float e6 = isB ? b6  : a6, e7 = isB ? b7  : a7;
        v0 = fmaf(e0 + bf_lo(us.x), dv, b2[8*c+0]);
        v1 = fmaf(e1 + bf_hi(us.x), dv, b2[8*c+1]);
        v2 = fmaf(e2 + bf_lo(us.y), dv, b2[8*c+2]);
        v3 = fmaf(e3 + bf_hi(us.y), dv, b2[8*c+3]);
        v4 = fmaf(e4 + bf_lo(us.z), dv, b2[8*c+4]);
        v5 = fmaf(e5 + bf_hi(us.z), dv, b2[8*c+5]);
        v6 = fmaf(e6 + bf_lo(us.w), dv, b2[8*c+6]);
        v7 = fmaf(e7 + bf_hi(us.w), dv, b2[8*c+7]);
    }
    float mx = fmaxf(fmaxf(fmaxf(v0, v1), fmaxf(v2, v3)),
                     fmaxf(fmaxf(v4, v5), fmaxf(v6, v7)));
#pragma unroll
    for (int off = 1; off <= 4; off <<= 1) mx = fmaxf(mx, __shfl_xor(mx, off));
    float ex = 0.f;
    if (act)
        ex = expf(v0-mx)+expf(v1-mx)+expf(v2-mx)+expf(v3-mx)
           + expf(v4-mx)+expf(v5-mx)+expf(v6-mx)+expf(v7-mx);
#pragma unroll
    for (int off = 1; off <= 4; off <<= 1) ex += __shfl_xor(ex, off);
    float lg = logf(ex);
    if (act && (g == 0 || g == 4)) {
        float4 o0, o1;
        o0.x = v0-mx-lg; o0.y = v1-mx-lg; o0.z = v2-mx-lg; o0.w = v3-mx-lg;
        o1.x = v4-mx-lg; o1.y = v5-mx-lg; o1.z = v6-mx-lg; o1.w = v7-mx-lg;
        float4* dst = reinterpret_cast<float4*>(&out[(size_t)nd * F_OUT + 8 * c]);
        dst[0] = o0;
        dst[1] = o1;
    }
}

extern "C" void kernel_launch(void* const* d_in, const int* in_sizes, int n_in,
                              void* d_out, int out_size, void* d_ws, size_t ws_size,
                              hipStream_t stream) {
    const float* x  = (const float*)d_in[0];
    const int*   ei = (const int*)d_in[1];
    const float* W1 = (const float*)d_in[2];
    const float* b1 = (const float*)d_in[3];
    const float* W2 = (const float*)d_in[4];
    const float* b2 = (const float*)d_in[5];
    float* out = (float*)d_out;

    const int n = in_sizes[0] / F_IN;
    const int E = in_sizes[1] / 2;
    const int* row = ei;
    const int* col = ei + E;
    const int nb = (n + BSZ - 1) / BSZ;   // 391 for n=100K

    char* p = (char*)d_ws;
    float*    dinv = (float*)p;     p += (size_t)n * 4;
    int*      beg  = (int*)p;       p += (size_t)n * 4;
    int*      deg  = (int*)p;       p += (size_t)n * 4;
    int*      gcur = (int*)p;       p += NB_MAX * 4;
    unsigned* w1f  = (unsigned*)p;  p += 16 * 64 * 4 * 4;
    unsigned* bbuf = (unsigned*)p;  p += (size_t)nb * CAP * 4;
    int*      srow = (int*)p;       p += (size_t)nb * CAP * 4;
    unsigned* h1b  = (unsigned*)p;  p += (size_t)(n + 1) * 32 * 4;   // 128B rows (+dummy)
    unsigned* h2b  = (unsigned*)p;  p += (size_t)(n + 1) * 32 * 4;   // 128B-padded rows (+dummy)

    k_w1frag<<<4, 256, 0, stream>>>(W1, w1f, h1b, h2b, gcur, n);
    k_partition<<<640, 256, 0, stream>>>(row, col, E, nb, gcur, bbuf);
    k_csr<<<nb, 1024, 0, stream>>>(bbuf, gcur, beg, deg, dinv, srow, n);
    k_lin1<<<(n + 63) / 64, 256, 0, stream>>>(x, w1f, dinv, h1b, n);
    k_agg1<<<(n + 7) / 8, 256, 0, stream>>>((const u4v*)h1b, beg, deg, srow, dinv, b1, W2, h2b, n);
    k_agg2<<<(n + 7) / 8, 256, 0, stream>>>((const u4v*)h2b, beg, deg, srow, dinv, b2, out, n);
}

// Round 16
// 444.310 us; speedup vs baseline: 1.0285x; 1.0285x over previous
//
#include <hip/hip_runtime.h>

#define F_IN  128
#define F_HID 64
#define F_OUT 40
#define BSZ   256          // nodes per bucket
#define BSH   8            // log2(BSZ)
#define NB_MAX 512
#define CAP   12288        // bucket region capacity (mean 8163, sigma ~90)

typedef __attribute__((ext_vector_type(8))) short v8s;      // 8 bf16 (4 VGPRs)
typedef __attribute__((ext_vector_type(4))) float v4f;      // 4 fp32 acc
typedef __attribute__((ext_vector_type(4))) unsigned u4v;   // native uint4

// pack two floats as bf16 pair (round-to-nearest-even): low16 = a, high16 = b
static __device__ __forceinline__ unsigned pack_bf16(float a, float b) {
    unsigned ua = __float_as_uint(a);
    unsigned ub = __float_as_uint(b);
    ua = (ua + 0x7fffu + ((ua >> 16) & 1u)) >> 16;
    ub = (ub + 0x7fffu + ((ub >> 16) & 1u)) & 0xffff0000u;
    return ua | ub;
}
static __device__ __forceinline__ float bf_lo(unsigned u) { return __uint_as_float(u << 16); }
static __device__ __forceinline__ float bf_hi(unsigned u) { return __uint_as_float(u & 0xffff0000u); }

// ---------------- partition edges into destination buckets ----------------
__global__ void k_partition(const int* __restrict__ row, const int* __restrict__ col,
                            int E, int nb, int* __restrict__ gcur,
                            unsigned* __restrict__ bbuf) {
    __shared__ int hist[NB_MAX];
    __shared__ int cur[NB_MAX];
    int t = threadIdx.x;
    for (int i = t; i < nb; i += 256) hist[i] = 0;
    __syncthreads();
    int chunk = (E + gridDim.x - 1) / gridDim.x;
    int e0 = blockIdx.x * chunk;
    int e1 = min(E, e0 + chunk);
    for (int e = e0 + t; e < e1; e += 256)
        atomicAdd(&hist[col[e] >> BSH], 1);
    __syncthreads();
    for (int i = t; i < nb; i += 256)
        cur[i] = i * CAP + atomicAdd(&gcur[i], hist[i]);
    __syncthreads();
    for (int e = e0 + t; e < e1; e += 256) {
        int c = col[e];
        int b = c >> BSH;
        int pos = atomicAdd(&cur[b], 1);
        if (pos < (b + 1) * CAP)
            bbuf[pos] = ((unsigned)row[e] << BSH) | (unsigned)(c & (BSZ - 1));
    }
}

// ---------------- per-bucket counting sort -> bucket-relative CSR ----------------
__global__ void __launch_bounds__(1024)
k_csr(const unsigned* __restrict__ bbuf, const int* __restrict__ gcur,
      int* __restrict__ beg, int* __restrict__ deg, float* __restrict__ dinv,
      int* __restrict__ srow, int n) {
    __shared__ unsigned pay[CAP];   // 48 KB
    __shared__ int cnt[BSZ];
    __shared__ int cur[BSZ];
    int b = blockIdx.x, t = threadIdx.x;
    int nE = min(gcur[b], CAP);
    int base = b * CAP;
    if (t < BSZ) cnt[t] = 0;
    __syncthreads();
    for (int i = t; i < nE; i += 1024) {
        unsigned u = bbuf[base + i];
        pay[i] = u;
        atomicAdd(&cnt[u & (BSZ - 1)], 1);
    }
    __syncthreads();
    if (t < BSZ) cur[t] = cnt[t];
    __syncthreads();
    for (int off = 1; off < BSZ; off <<= 1) {
        int add = (t < BSZ && t >= off) ? cur[t - off] : 0;
        __syncthreads();
        if (t < BSZ) cur[t] += add;
        __syncthreads();
    }
    int node0 = b * BSZ;
    if (t < BSZ) {
        int ex = cur[t] - cnt[t];
        int node = node0 + t;
        if (node < n) {
            beg[node] = base + ex;
            deg[node] = cnt[t];
            dinv[node] = rsqrtf((float)cnt[t] + 1.0f);
        }
        cur[t] = ex;
    }
    __syncthreads();
    for (int i = t; i < nE; i += 1024) {
        unsigned u = pay[i];
        int pos = atomicAdd(&cur[u & (BSZ - 1)], 1);
        srow[base + pos] = (int)(u >> BSH);
    }
}

// ---------------- W1 fragments + zero dummy rows + zero gcur (runs first) ----------------
__global__ void k_w1frag(const float* __restrict__ W1, unsigned* __restrict__ w1f,
                         unsigned* __restrict__ h1b, unsigned* __restrict__ h2b,
                         int* __restrict__ gcur, int n) {
    int gid = blockIdx.x * 256 + threadIdx.x;
    if (gid < 32) h1b[(size_t)n * 32 + gid] = 0u;        // dummy zero row (layer 1)
    if (gid < 32) h2b[(size_t)n * 32 + gid] = 0u;        // dummy zero row (layer 2)
    if (gid < NB_MAX) gcur[gid] = 0;
    if (gid >= 16 * 64) return;
    int f = gid >> 6, l = gid & 63;
    int j0 = f >> 2, ks = f & 3;
    int col = 16 * j0 + (l & 15);
    int kb = ks * 32 + ((l >> 4) << 3);
#pragma unroll
    for (int d = 0; d < 4; ++d) {
        float a = W1[(kb + 2 * d) * F_HID + col];
        float b = W1[(kb + 2 * d + 1) * F_HID + col];
        w1f[(size_t)gid * 4 + d] = pack_bf16(a, b);
    }
}

// ---------------- layer 1 linear via MFMA: h1b = bf16( dinv * (x @ W1) ) ----------------
__global__ void k_lin1(const float* __restrict__ x, const unsigned* __restrict__ w1f,
                       const float* __restrict__ dinv, unsigned* __restrict__ h1b, int n) {
    int t = threadIdx.x;
    int l = t & 63, w = t >> 6;
    int node0 = blockIdx.x * 64 + w * 16;
    int arow = min(node0 + (l & 15), n - 1);   // clamped A-row (safe OOB)
    const u4v* wf4 = (const u4v*)w1f;
    v8s bf[16];
#pragma unroll
    for (int f = 0; f < 16; ++f) {
        u4v u = wf4[f * 64 + l];
        bf[f] = *(v8s*)&u;
    }
    v8s af[4];
#pragma unroll
    for (int ks = 0; ks < 4; ++ks) {
        int kb = ks * 32 + ((l >> 4) << 3);
        const float4* xp = (const float4*)&x[(size_t)arow * F_IN + kb];
        float4 x0 = xp[0], x1 = xp[1];
        u4v uu = { pack_bf16(x0.x, x0.y), pack_bf16(x0.z, x0.w),
                   pack_bf16(x1.x, x1.y), pack_bf16(x1.z, x1.w) };
        af[ks] = *(v8s*)&uu;
    }
#pragma unroll
    for (int j0 = 0; j0 < 4; ++j0) {
        v4f acc = {0.f, 0.f, 0.f, 0.f};
#pragma unroll
        for (int ks = 0; ks < 4; ++ks)
            acc = __builtin_amdgcn_mfma_f32_16x16x32_bf16(af[ks], bf[j0 * 4 + ks], acc, 0, 0, 0);
#pragma unroll
        for (int i = 0; i < 4; ++i) {
            int node = node0 + ((l >> 4) << 2) + i;
            float s = acc[i] * dinv[min(node, n - 1)];
            float pr = __shfl_xor(s, 1);
            if (!(l & 1) && node < n)
                h1b[(size_t)node * 32 + 8 * j0 + ((l & 15) >> 1)] = pack_bf16(s, pr);
        }
    }
}

// gathers: out-of-range lanes carry the dummy row index (n), whose row is zero.
#define ISS(tq, rv, i, u) { int rr = __shfl(rv, (i) * 8 + g); u = tq[(size_t)rr * 8 + c]; }
#define ACC(u, p0,p1,p2,p3,p4,p5,p6,p7) { \
    p0 += bf_lo(u.x); p1 += bf_hi(u.x); p2 += bf_lo(u.y); p3 += bf_hi(u.y); \
    p4 += bf_lo(u.z); p5 += bf_hi(u.z); p6 += bf_lo(u.w); p7 += bf_hi(u.w); }
#define RED(p) { p += __shfl_xor(p, 8); p += __shfl_xor(p, 16); p += __shfl_xor(p, 32); }

// ---------------- layer-1 aggregation (2 nodes/wave, 8 lines in flight) + relu + W2 GEMM ----------------
// __launch_bounds__(256,4): 128-VGPR budget, prevents the R15 spill (16 acc + 32 in-flight regs)
__global__ void __launch_bounds__(256, 4)
k_agg1(const u4v* __restrict__ h1q, const int* __restrict__ beg,
       const int* __restrict__ deg, const int* __restrict__ srow,
       const float* __restrict__ dinv, const float* __restrict__ b1,
       const float* __restrict__ W2, unsigned* __restrict__ h2b, int n) {
    __shared__ float W2s[F_HID * F_OUT];  // 10 KB
    __shared__ float b1s[F_HID];
    __shared__ float zrow[8][F_HID];      // 2 KB
    int t = threadIdx.x;
    for (int i = t; i < F_HID * F_OUT; i += 256) W2s[i] = W2[i];
    if (t < F_HID) b1s[t] = b1[t];
    __syncthreads();
    int lane = t & 63, w = t >> 6;
    int g = lane >> 3, c = lane & 7;
    int nA = blockIdx.x * 8 + w * 2;
    if (nA >= n) return;
    int nB = nA + 1;
    bool hasB = nB < n;
    int bgA = beg[nA], cntA = deg[nA];
    int bgB = hasB ? beg[nB] : 0, cntB = hasB ? deg[nB] : 0;
    float a0=0,a1=0,a2=0,a3=0,a4=0,a5=0,a6=0,a7=0;
    float b0=0,b1_=0,b2_=0,b3=0,b4=0,b5=0,b6=0,b7=0;
    int cmax = max(cntA, cntB);
    for (int e0 = 0; e0 < cmax; e0 += 64) {
        int rA = (lane < cntA - e0) ? srow[bgA + e0 + lane] : n;
        int rB = (lane < cntB - e0) ? srow[bgB + e0 + lane] : n;
        int iters = (min(cmax - e0, 64) + 7) >> 3;
        u4v uA0, uA1, uA2, uA3, uB0, uB1, uB2, uB3;
        ISS(h1q, rA, 0, uA0) ISS(h1q, rB, 0, uB0)
        ISS(h1q, rA, 1, uA1) ISS(h1q, rB, 1, uB1)
        ISS(h1q, rA, 2, uA2) ISS(h1q, rB, 2, uB2)
        ISS(h1q, rA, 3, uA3) ISS(h1q, rB, 3, uB3)
        ACC(uA0, a0,a1,a2,a3,a4,a5,a6,a7) ACC(uB0, b0,b1_,b2_,b3,b4,b5,b6,b7)
        ACC(uA1, a0,a1,a2,a3,a4,a5,a6,a7) ACC(uB1, b0,b1_,b2_,b3,b4,b5,b6,b7)
        ACC(uA2, a0,a1,a2,a3,a4,a5,a6,a7) ACC(uB2, b0,b1_,b2_,b3,b4,b5,b6,b7)
        ACC(uA3, a0,a1,a2,a3,a4,a5,a6,a7) ACC(uB3, b0,b1_,b2_,b3,b4,b5,b6,b7)
        if (iters > 4) {
            ISS(h1q, rA, 4, uA0) ISS(h1q, rB, 4, uB0)
            if (iters > 5) { ISS(h1q, rA, 5, uA1) ISS(h1q, rB, 5, uB1) }
            if (iters > 6) { ISS(h1q, rA, 6, uA2) ISS(h1q, rB, 6, uB2) }
            if (iters > 7) { ISS(h1q, rA, 7, uA3) ISS(h1q, rB, 7, uB3) }
            ACC(uA0, a0,a1,a2,a3,a4,a5,a6,a7) ACC(uB0, b0,b1_,b2_,b3,b4,b5,b6,b7)
            if (iters > 5) { ACC(uA1, a0,a1,a2,a3,a4,a5,a6,a7) ACC(uB1, b0,b1_,b2_,b3,b4,b5,b6,b7) }
            if (iters > 6) { ACC(uA2, a0,a1,a2,a3,a4,a5,a6,a7) ACC(uB2, b0,b1_,b2_,b3,b4,b5,b6,b7) }
            if (iters > 7) { ACC(uA3, a0,a1,a2,a3,a4,a5,a6,a7) ACC(uB3, b0,b1_,b2_,b3,b4,b5,b6,b7) }
        }
    }
    RED(a0) RED(a1) RED(a2) RED(a3) RED(a4) RED(a5) RED(a6) RED(a7)
    RED(b0) RED(b1_) RED(b2_) RED(b3) RED(b4) RED(b5) RED(b6) RED(b7)
    if (g == 0) {               // node A: self-loop + relu -> zrow[2w]
        u4v us = h1q[(size_t)nA * 8 + c];
        float dv = dinv[nA];
        float z;
        z = fmaf(a0 + bf_lo(us.x), dv, b1s[8*c+0]); zrow[2*w][8*c+0] = z > 0.f ? z : 0.f;
        z = fmaf(a1 + bf_hi(us.x), dv, b1s[8*c+1]); zrow[2*w][8*c+1] = z > 0.f ? z : 0.f;
        z = fmaf(a2 + bf_lo(us.y), dv, b1s[8*c+2]); zrow[2*w][8*c+2] = z > 0.f ? z : 0.f;
        z = fmaf(a3 + bf_hi(us.y), dv, b1s[8*c+3]); zrow[2*w][8*c+3] = z > 0.f ? z : 0.f;
        z = fmaf(a4 + bf_lo(us.z), dv, b1s[8*c+4]); zrow[2*w][8*c+4] = z > 0.f ? z : 0.f;
        z = fmaf(a5 + bf_hi(us.z), dv, b1s[8*c+5]); zrow[2*w][8*c+5] = z > 0.f ? z : 0.f;
        z = fmaf(a6 + bf_lo(us.w), dv, b1s[8*c+6]); zrow[2*w][8*c+6] = z > 0.f ? z : 0.f;
        z = fmaf(a7 + bf_hi(us.w), dv, b1s[8*c+7]); zrow[2*w][8*c+7] = z > 0.f ? z : 0.f;
    } else if (g == 1 && hasB) {  // node B: self-loop + relu -> zrow[2w+1]
        u4v us = h1q[(size_t)nB * 8 + c];
        float dv = dinv[nB];
        float z;
        z = fmaf(b0  + bf_lo(us.x), dv, b1s[8*c+0]); zrow[2*w+1][8*c+0] = z > 0.f ? z : 0.f;
        z = fmaf(b1_ + bf_hi(us.x), dv, b1s[8*c+1]); zrow[2*w+1][8*c+1] = z > 0.f ? z : 0.f;
        z = fmaf(b2_ + bf_lo(us.y), dv, b1s[8*c+2]); zrow[2*w+1][8*c+2] = z > 0.f ? z : 0.f;
        z = fmaf(b3  + bf_hi(us.y), dv, b1s[8*c+3]); zrow[2*w+1][8*c+3] = z > 0.f ? z : 0.f;
        z = fmaf(b4  + bf_lo(us.z), dv, b1s[8*c+4]); zrow[2*w+1][8*c+4] = z > 0.f ? z : 0.f;
        z = fmaf(b5  + bf_hi(us.z), dv, b1s[8*c+5]); zrow[2*w+1][8*c+5] = z > 0.f ? z : 0.f;
        z = fmaf(b6  + bf_lo(us.w), dv, b1s[8*c+6]); zrow[2*w+1][8*c+6] = z > 0.f ? z : 0.f;
        z = fmaf(b7  + bf_hi(us.w), dv, b1s[8*c+7]); zrow[2*w+1][8*c+7] = z > 0.f ? z : 0.f;
    }
    // same-wave DS write->read (in-order DS pipe); two W2 dots per wave
    float sA = 0.f, sB = 0.f;
    if (lane < F_OUT) {
#pragma unroll
        for (int k = 0; k < F_HID; ++k) {
            sA = fmaf(zrow[2*w][k],   W2s[k * F_OUT + lane], sA);
            sB = fmaf(zrow[2*w+1][k], W2s[k * F_OUT + lane], sB);
        }
        sA *= dinv[nA];
        sB *= hasB ? dinv[nB] : 0.f;
    }
    float pA = __shfl_xor(sA, 1);
    float pB = __shfl_xor(sB, 1);
    if (lane < F_OUT && (lane & 1) == 0) {
        h2b[(size_t)nA * 32 + (lane >> 1)] = pack_bf16(sA, pA);
        if (hasB) h2b[(size_t)nB * 32 + (lane >> 1)] = pack_bf16(sB, pB);
    }
}

// ---------------- layer-2 aggregation (2 nodes/wave) + bias + fused log_softmax ----------------
__global__ void __launch_bounds__(256, 4)
k_agg2(const u4v* __restrict__ h2q, const int* __restrict__ beg,
       const int* __restrict__ deg, const int* __restrict__ srow,
       const float* __restrict__ dinv, const float* __restrict__ b2,
       float* __restrict__ out, int n) {
    int t = threadIdx.x, lane = t & 63, w = t >> 6;
    int g = lane >> 3, c = lane & 7;
    int nA = blockIdx.x * 8 + w * 2;
    if (nA >= n) return;
    int nB = nA + 1;
    bool hasB = nB < n;
    int bgA = beg[nA], cntA = deg[nA];
    int bgB = hasB ? beg[nB] : 0, cntB = hasB ? deg[nB] : 0;
    float a0=0,a1=0,a2=0,a3=0,a4=0,a5=0,a6=0,a7=0;
    float b0=0,b1_=0,b2_=0,b3=0,b4=0,b5=0,b6=0,b7=0;
    int cmax = max(cntA, cntB);
    for (int e0 = 0; e0 < cmax; e0 += 64) {
        int rA = (lane < cntA - e0) ? srow[bgA + e0 + lane] : n;
        int rB = (lane < cntB - e0) ? srow[bgB + e0 + lane] : n;
        int iters = (min(cmax - e0, 64) + 7) >> 3;
        u4v uA0, uA1, uA2, uA3, uB0, uB1, uB2, uB3;
        ISS(h2q, rA, 0, uA0) ISS(h2q, rB, 0, uB0)
        ISS(h2q, rA, 1, uA1) ISS(h2q, rB, 1, uB1)
        ISS(h2q, rA, 2, uA2) ISS(h2q, rB, 2, uB2)
        ISS(h2q, rA, 3, uA3) ISS(h2q, rB, 3, uB3)
        ACC(uA0, a0,a1,a2,a3,a4,a5,a6,a7) ACC(uB0, b0,b1_,b2_,b3,b4,b5,b6,b7)
        ACC(uA1, a0,a1,a2,a3,a4,a5,a6,a7) ACC(uB1, b0,b1_,b2_,b3,b4,b5,b6,b7)
        ACC(uA2, a0,a1,a2,a3,a4,a5,a6,a7) ACC(uB2, b0,b1_,b2_,b3,b4,b5,b6,b7)
        ACC(uA3, a0,a1,a2,a3,a4,a5,a6,a7) ACC(uB3, b0,b1_,b2_,b3,b4,b5,b6,b7)
        if (iters > 4) {
            ISS(h2q, rA, 4, uA0) ISS(h2q, rB, 4, uB0)
            if (iters > 5) { ISS(h2q, rA, 5, uA1) ISS(h2q, rB, 5, uB1) }
            if (iters > 6) { ISS(h2q, rA, 6, uA2) ISS(h2q, rB, 6, uB2) }
            if (iters > 7) { ISS(h2q, rA, 7, uA3) ISS(h2q, rB, 7, uB3) }
            ACC(uA0, a0,a1,a2,a3,a4,a5,a6,a7) ACC(uB0, b0,b1_,b2_,b3,b4,b5,b6,b7)
            if (iters > 5) { ACC(uA1, a0,a1,a2,a3,a4,a5,a6,a7) ACC(uB1, b0,b1_,b2_,b3,b4,b5,b6,b7) }
            if (iters > 6) { ACC(uA2, a0,a1,a2,a3,a4,a5,a6,a7) ACC(uB2, b0,b1_,b2_,b3,b4,b5,b6,b7) }
            if (iters > 7) { ACC(uA3, a0,a1,a2,a3,a4,a5,a6,a7) ACC(uB3, b0,b1_,b2_,b3,b4,b5,b6,b7) }
        }
    }
    RED(a0) RED(a1) RED(a2) RED(a3) RED(a4) RED(a5) RED(a6) RED(a7)
    RED(b0) RED(b1_) RED(b2_) RED(b3) RED(b4) RED(b5) RED(b6) RED(b7)
    // lanes 0-31 finish node A, lanes 32-63 finish node B (each 8-lane c-group redundant)
    bool isB = g >= 4;
    int nd = isB ? nB : nA;
    bool nodeOK = !isB || hasB;
    bool act = (c < 5) && nodeOK;
    float v0=-1e30f,v1=-1e30f,v2=-1e30f,v3=-1e30f,v4=-1e30f,v5=-1e30f,v6=-1e30f,v7=-1e30f;
    if (act) {
        float dv = dinv[nd];
        u4v us = h2q[(size_t)nd * 8 + c];   // self-loop
        float e0 = isB ? b0  : a0, e1 = isB ? b1_ : a1;
        float e2 = isB ? b2_ : a2, e3 = isB ? b3  : a3;
        float e4 = isB ? b4  : a4, e5 = isB ? b5  : a5;
        float e6 = isB ? b6  : a6, e7 = isB ? b7  : a7;
        v0 = fmaf(e0 + bf_lo(us.x), dv, b2[8*c+0]);
        v1 = fmaf(e1 + bf_hi(us.x), dv, b2[8*c+1]);
        v2 = fmaf(e2 + bf_lo(us.y), dv, b2[8*c+2]);
        v3 = fmaf(e3 + bf_hi(us.y), dv, b2[8*c+3]);
        v4 = fmaf(e4 + bf_lo(us.z), dv, b2[8*c+4]);
        v5 = fmaf(e5 + bf_hi(us.z), dv, b2[8*c+5]);
        v6 = fmaf(e6 + bf_lo(us.w), dv, b2[8*c+6]);
        v7 = fmaf(e7 + bf_hi(us.w), dv, b2[8*c+7]);
    }
    float mx = fmaxf(fmaxf(fmaxf(v0, v1), fmaxf(v2, v3)),
                     fmaxf(fmaxf(v4, v5), fmaxf(v6, v7)));
#pragma unroll
    for (int off = 1; off <= 4; off <<= 1) mx = fmaxf(mx, __shfl_xor(mx, off));
    float ex = 0.f;
    if (act)
        ex = expf(v0-mx)+expf(v1-mx)+expf(v2-mx)+expf(v3-mx)
           + expf(v4-mx)+expf(v5-mx)+expf(v6-mx)+expf(v7-mx);
#pragma unroll
    for (int off = 1; off <= 4; off <<= 1) ex += __shfl_xor(ex, off);
    float lg = logf(ex);
    if (act && (g == 0 || g == 4)) {
        float4 o0, o1;
        o0.x = v0-mx-lg; o0.y = v1-mx-lg; o0.z = v2-mx-lg; o0.w = v3-mx-lg;
        o1.x = v4-mx-lg; o1.y = v5-mx-lg; o1.z = v6-mx-lg; o1.w = v7-mx-lg;
        float4* dst = reinterpret_cast<float4*>(&out[(size_t)nd * F_OUT + 8 * c]);
        dst[0] = o0;
        dst[1] = o1;
    }
}

extern "C" void kernel_launch(void* const* d_in, const int* in_sizes, int n_in,
                              void* d_out, int out_size, void* d_ws, size_t ws_size,
                              hipStream_t stream) {
    const float* x  = (const float*)d_in[0];
    const int*   ei = (const int*)d_in[1];
    const float* W1 = (const float*)d_in[2];
    const float* b1 = (const float*)d_in[3];
    const float* W2 = (const float*)d_in[4];
    const float* b2 = (const float*)d_in[5];
    float* out = (float*)d_out;

    const int n = in_sizes[0] / F_IN;
    const int E = in_sizes[1] / 2;
    const int* row = ei;
    const int* col = ei + E;
    const int nb = (n + BSZ - 1) / BSZ;   // 391 for n=100K

    char* p = (char*)d_ws;
    float*    dinv = (float*)p;     p += (size_t)n * 4;
    int*      beg  = (int*)p;       p += (size_t)n * 4;
    int*      deg  = (int*)p;       p += (size_t)n * 4;
    int*      gcur = (int*)p;       p += NB_MAX * 4;
    unsigned* w1f  = (unsigned*)p;  p += 16 * 64 * 4 * 4;
    unsigned* bbuf = (unsigned*)p;  p += (size_t)nb * CAP * 4;
    int*      srow = (int*)p;       p += (size_t)nb * CAP * 4;
    unsigned* h1b  = (unsigned*)p;  p += (size_t)(n + 1) * 32 * 4;   // 128B rows (+dummy)
    unsigned* h2b  = (unsigned*)p;  p += (size_t)(n + 1) * 32 * 4;   // 128B-padded rows (+dummy)

    k_w1frag<<<4, 256, 0, stream>>>(W1, w1f, h1b, h2b, gcur, n);
    k_partition<<<640, 256, 0, stream>>>(row, col, E, nb, gcur, bbuf);
    k_csr<<<nb, 1024, 0, stream>>>(bbuf, gcur, beg, deg, dinv, srow, n);
    k_lin1<<<(n + 63) / 64, 256, 0, stream>>>(x, w1f, dinv, h1b, n);
    k_agg1<<<(n + 7) / 8, 256, 0, stream>>>((const u4v*)h1b, beg, deg, srow, dinv, b1, W2, h2b, n);
    k_agg2<<<(n + 7) / 8, 256, 0, stream>>>((const u4v*)h2b, beg, deg, srow, dinv, b2, out, n);
}

// Round 17
// 442.785 us; speedup vs baseline: 1.0321x; 1.0034x over previous
//
#include <hip/hip_runtime.h>

#define F_IN  128
#define F_HID 64
#define F_OUT 40
#define BSZ   256          // nodes per bucket
#define BSH   8            // log2(BSZ)
#define NB_MAX 512
#define CAP   12288        // bucket region capacity (mean 8163, sigma ~90)

typedef __attribute__((ext_vector_type(8))) short v8s;      // 8 bf16 (4 VGPRs)
typedef __attribute__((ext_vector_type(4))) float v4f;      // 4 fp32 acc
typedef __attribute__((ext_vector_type(4))) unsigned u4v;   // native uint4

// pack two floats as bf16 pair (round-to-nearest-even): low16 = a, high16 = b
static __device__ __forceinline__ unsigned pack_bf16(float a, float b) {
    unsigned ua = __float_as_uint(a);
    unsigned ub = __float_as_uint(b);
    ua = (ua + 0x7fffu + ((ua >> 16) & 1u)) >> 16;
    ub = (ub + 0x7fffu + ((ub >> 16) & 1u)) & 0xffff0000u;
    return ua | ub;
}
static __device__ __forceinline__ float bf_lo(unsigned u) { return __uint_as_float(u << 16); }
static __device__ __forceinline__ float bf_hi(unsigned u) { return __uint_as_float(u & 0xffff0000u); }

// ---------------- partition edges into destination buckets ----------------
__global__ void k_partition(const int* __restrict__ row, const int* __restrict__ col,
                            int E, int nb, int* __restrict__ gcur,
                            unsigned* __restrict__ bbuf) {
    __shared__ int hist[NB_MAX];
    __shared__ int cur[NB_MAX];
    int t = threadIdx.x;
    for (int i = t; i < nb; i += 256) hist[i] = 0;
    __syncthreads();
    int chunk = (E + gridDim.x - 1) / gridDim.x;
    int e0 = blockIdx.x * chunk;
    int e1 = min(E, e0 + chunk);
    for (int e = e0 + t; e < e1; e += 256)
        atomicAdd(&hist[col[e] >> BSH], 1);
    __syncthreads();
    for (int i = t; i < nb; i += 256)
        cur[i] = i * CAP + atomicAdd(&gcur[i], hist[i]);
    __syncthreads();
    for (int e = e0 + t; e < e1; e += 256) {
        int c = col[e];
        int b = c >> BSH;
        int pos = atomicAdd(&cur[b], 1);
        if (pos < (b + 1) * CAP)
            bbuf[pos] = ((unsigned)row[e] << BSH) | (unsigned)(c & (BSZ - 1));
    }
}

// ---------------- per-bucket counting sort -> bucket-relative CSR ----------------
__global__ void __launch_bounds__(1024)
k_csr(const unsigned* __restrict__ bbuf, const int* __restrict__ gcur,
      int* __restrict__ beg, int* __restrict__ deg, float* __restrict__ dinv,
      int* __restrict__ srow, int n) {
    __shared__ unsigned pay[CAP];   // 48 KB
    __shared__ int cnt[BSZ];
    __shared__ int cur[BSZ];
    int b = blockIdx.x, t = threadIdx.x;
    int nE = min(gcur[b], CAP);
    int base = b * CAP;
    if (t < BSZ) cnt[t] = 0;
    __syncthreads();
    for (int i = t; i < nE; i += 1024) {
        unsigned u = bbuf[base + i];
        pay[i] = u;
        atomicAdd(&cnt[u & (BSZ - 1)], 1);
    }
    __syncthreads();
    if (t < BSZ) cur[t] = cnt[t];
    __syncthreads();
    for (int off = 1; off < BSZ; off <<= 1) {
        int add = (t < BSZ && t >= off) ? cur[t - off] : 0;
        __syncthreads();
        if (t < BSZ) cur[t] += add;
        __syncthreads();
    }
    int node0 = b * BSZ;
    if (t < BSZ) {
        int ex = cur[t] - cnt[t];
        int node = node0 + t;
        if (node < n) {
            beg[node] = base + ex;
            deg[node] = cnt[t];
            dinv[node] = rsqrtf((float)cnt[t] + 1.0f);
        }
        cur[t] = ex;
    }
    __syncthreads();
    for (int i = t; i < nE; i += 1024) {
        unsigned u = pay[i];
        int pos = atomicAdd(&cur[u & (BSZ - 1)], 1);
        srow[base + pos] = (int)(u >> BSH);
    }
}

// ---------------- W1 fragments + zero dummy rows + zero gcur (runs first) ----------------
__global__ void k_w1frag(const float* __restrict__ W1, unsigned* __restrict__ w1f,
                         unsigned* __restrict__ h1b, unsigned* __restrict__ h2b,
                         int* __restrict__ gcur, int n) {
    int gid = blockIdx.x * 256 + threadIdx.x;
    if (gid < 32) h1b[(size_t)n * 32 + gid] = 0u;        // dummy zero row (layer 1)
    if (gid < 32) h2b[(size_t)n * 32 + gid] = 0u;        // dummy zero row (layer 2)
    if (gid < NB_MAX) gcur[gid] = 0;
    if (gid >= 16 * 64) return;
    int f = gid >> 6, l = gid & 63;
    int j0 = f >> 2, ks = f & 3;
    int col = 16 * j0 + (l & 15);
    int kb = ks * 32 + ((l >> 4) << 3);
#pragma unroll
    for (int d = 0; d < 4; ++d) {
        float a = W1[(kb + 2 * d) * F_HID + col];
        float b = W1[(kb + 2 * d + 1) * F_HID + col];
        w1f[(size_t)gid * 4 + d] = pack_bf16(a, b);
    }
}

// ---------------- layer 1 linear via MFMA: h1b = bf16( dinv * (x @ W1) ) ----------------
__global__ void k_lin1(const float* __restrict__ x, const unsigned* __restrict__ w1f,
                       const float* __restrict__ dinv, unsigned* __restrict__ h1b, int n) {
    int t = threadIdx.x;
    int l = t & 63, w = t >> 6;
    int node0 = blockIdx.x * 64 + w * 16;
    int arow = min(node0 + (l & 15), n - 1);   // clamped A-row (safe OOB)
    const u4v* wf4 = (const u4v*)w1f;
    v8s bf[16];
#pragma unroll
    for (int f = 0; f < 16; ++f) {
        u4v u = wf4[f * 64 + l];
        bf[f] = *(v8s*)&u;
    }
    v8s af[4];
#pragma unroll
    for (int ks = 0; ks < 4; ++ks) {
        int kb = ks * 32 + ((l >> 4) << 3);
        const float4* xp = (const float4*)&x[(size_t)arow * F_IN + kb];
        float4 x0 = xp[0], x1 = xp[1];
        u4v uu = { pack_bf16(x0.x, x0.y), pack_bf16(x0.z, x0.w),
                   pack_bf16(x1.x, x1.y), pack_bf16(x1.z, x1.w) };
        af[ks] = *(v8s*)&uu;
    }
#pragma unroll
    for (int j0 = 0; j0 < 4; ++j0) {
        v4f acc = {0.f, 0.f, 0.f, 0.f};
#pragma unroll
        for (int ks = 0; ks < 4; ++ks)
            acc = __builtin_amdgcn_mfma_f32_16x16x32_bf16(af[ks], bf[j0 * 4 + ks], acc, 0, 0, 0);
#pragma unroll
        for (int i = 0; i < 4; ++i) {
            int node = node0 + ((l >> 4) << 2) + i;
            float s = acc[i] * dinv[min(node, n - 1)];
            float pr = __shfl_xor(s, 1);
            if (!(l & 1) && node < n)
                h1b[(size_t)node * 32 + 8 * j0 + ((l & 15) >> 1)] = pack_bf16(s, pr);
        }
    }
}

// half-wave split gathers: lanes 0-31 node A, lanes 32-63 node B.
// One ISS instruction fetches TWO 128B lines (one per half) -> 8 lines in flight at 4 u4v regs.
// out-of-range lanes carry dummy row index (n), whose row is zero.
#define ISS(tq, i, u) { int rr = __shfl(r, hb + (i) * 4 + gg); u = tq[(size_t)rr * 8 + c]; }
#define ACC8(u) { a0 += bf_lo(u.x); a1 += bf_hi(u.x); a2 += bf_lo(u.y); a3 += bf_hi(u.y); \
                  a4 += bf_lo(u.z); a5 += bf_hi(u.z); a6 += bf_lo(u.w); a7 += bf_hi(u.w); }
#define RED2(p) { p += __shfl_xor(p, 8); p += __shfl_xor(p, 16); }

// ---------------- layer-1 aggregation (2 nodes/wave, half-split) + relu + W2 GEMM ----------------
__global__ void k_agg1(const u4v* __restrict__ h1q, const int* __restrict__ beg,
                       const int* __restrict__ deg, const int* __restrict__ srow,
                       const float* __restrict__ dinv, const float* __restrict__ b1,
                       const float* __restrict__ W2, unsigned* __restrict__ h2b, int n) {
    __shared__ float W2s[F_HID * F_OUT];  // 10 KB
    __shared__ float b1s[F_HID];
    __shared__ float zrow[8][F_HID];      // 2 KB
    int t = threadIdx.x;
    for (int i = t; i < F_HID * F_OUT; i += 256) W2s[i] = W2[i];
    if (t < F_HID) b1s[t] = b1[t];
    __syncthreads();
    int lane = t & 63, w = t >> 6;
    int h = lane >> 5, l5 = lane & 31;
    int gg = (lane >> 3) & 3, c = lane & 7;
    int hb = h << 5;
    int nA = blockIdx.x * 8 + w * 2;
    if (nA >= n) return;
    int nB = nA + 1;
    bool hasB = nB < n;
    int nd = h ? nB : nA;
    bool ok = (h == 0) || hasB;
    int bg = ok ? beg[nd] : 0;
    int cnt = ok ? deg[nd] : 0;
    int cmax = max(__shfl(cnt, 0), __shfl(cnt, 32));
    float a0=0,a1=0,a2=0,a3=0,a4=0,a5=0,a6=0,a7=0;
    for (int e0 = 0; e0 < cmax; e0 += 32) {
        int r = (l5 < cnt - e0) ? srow[bg + e0 + l5] : n;   // own half's edges (dummy pad)
        int iters = (min(cmax - e0, 32) + 3) >> 2;          // 1..8 rounds of 4 edges/half
        u4v u0, u1, u2, u3;
        ISS(h1q, 0, u0) ISS(h1q, 1, u1) ISS(h1q, 2, u2) ISS(h1q, 3, u3)
        ACC8(u0)
        if (iters > 1) ACC8(u1)
        if (iters > 2) ACC8(u2)
        if (iters > 3) ACC8(u3)
        if (iters > 4) {
            ISS(h1q, 4, u0)
            if (iters > 5) ISS(h1q, 5, u1)
            if (iters > 6) ISS(h1q, 6, u2)
            if (iters > 7) ISS(h1q, 7, u3)
            ACC8(u0)
            if (iters > 5) ACC8(u1)
            if (iters > 6) ACC8(u2)
            if (iters > 7) ACC8(u3)
        }
    }
    RED2(a0) RED2(a1) RED2(a2) RED2(a3) RED2(a4) RED2(a5) RED2(a6) RED2(a7)
    if (gg == 0 && ok) {     // lanes 0-7: node A; lanes 32-39: node B
        u4v us = h1q[(size_t)nd * 8 + c];   // self-loop (already dinv-scaled)
        float dv = dinv[nd];
        float z;
        z = fmaf(a0 + bf_lo(us.x), dv, b1s[8*c+0]); zrow[2*w+h][8*c+0] = z > 0.f ? z : 0.f;
        z = fmaf(a1 + bf_hi(us.x), dv, b1s[8*c+1]); zrow[2*w+h][8*c+1] = z > 0.f ? z : 0.f;
        z = fmaf(a2 + bf_lo(us.y), dv, b1s[8*c+2]); zrow[2*w+h][8*c+2] = z > 0.f ? z : 0.f;
        z = fmaf(a3 + bf_hi(us.y), dv, b1s[8*c+3]); zrow[2*w+h][8*c+3] = z > 0.f ? z : 0.f;
        z = fmaf(a4 + bf_lo(us.z), dv, b1s[8*c+4]); zrow[2*w+h][8*c+4] = z > 0.f ? z : 0.f;
        z = fmaf(a5 + bf_hi(us.z), dv, b1s[8*c+5]); zrow[2*w+h][8*c+5] = z > 0.f ? z : 0.f;
        z = fmaf(a6 + bf_lo(us.w), dv, b1s[8*c+6]); zrow[2*w+h][8*c+6] = z > 0.f ? z : 0.f;
        z = fmaf(a7 + bf_hi(us.w), dv, b1s[8*c+7]); zrow[2*w+h][8*c+7] = z > 0.f ? z : 0.f;
    }
    // same-wave DS write->read (in-order DS pipe); two W2 dots per wave
    float sA = 0.f, sB = 0.f;
    if (lane < F_OUT) {
#pragma unroll
        for (int k = 0; k < F_HID; ++k) {
            sA = fmaf(zrow[2*w][k],   W2s[k * F_OUT + lane], sA);
            sB = fmaf(zrow[2*w+1][k], W2s[k * F_OUT + lane], sB);
        }
        sA *= dinv[nA];
        sB *= hasB ? dinv[nB] : 0.f;
    }
    float pA = __shfl_xor(sA, 1);
    float pB = __shfl_xor(sB, 1);
    if (lane < F_OUT && (lane & 1) == 0) {
        h2b[(size_t)nA * 32 + (lane >> 1)] = pack_bf16(sA, pA);
        if (hasB) h2b[(size_t)nB * 32 + (lane >> 1)] = pack_bf16(sB, pB);
    }
}

// ---------------- layer-2 aggregation (2 nodes/wave, half-split) + bias + log_softmax ----------------
__global__ void k_agg2(const u4v* __restrict__ h2q, const int* __restrict__ beg,
                       const int* __restrict__ deg, const int* __restrict__ srow,
                       const float* __restrict__ dinv, const float* __restrict__ b2,
                       float* __restrict__ out, int n) {
    int t = threadIdx.x, lane = t & 63, w = t >> 6;
    int h = lane >> 5, l5 = lane & 31;
    int gg = (lane >> 3) & 3, c = lane & 7;
    int hb = h << 5;
    int nA = blockIdx.x * 8 + w * 2;
    if (nA >= n) return;
    int nB = nA + 1;
    bool hasB = nB < n;
    int nd = h ? nB : nA;
    bool ok = (h == 0) || hasB;
    int bg = ok ? beg[nd] : 0;
    int cnt = ok ? deg[nd] : 0;
    int cmax = max(__shfl(cnt, 0), __shfl(cnt, 32));
    float a0=0,a1=0,a2=0,a3=0,a4=0,a5=0,a6=0,a7=0;
    for (int e0 = 0; e0 < cmax; e0 += 32) {
        int r = (l5 < cnt - e0) ? srow[bg + e0 + l5] : n;   // dummy pad
        int iters = (min(cmax - e0, 32) + 3) >> 2;
        u4v u0, u1, u2, u3;
        ISS(h2q, 0, u0) ISS(h2q, 1, u1) ISS(h2q, 2, u2) ISS(h2q, 3, u3)
        ACC8(u0)
        if (iters > 1) ACC8(u1)
        if (iters > 2) ACC8(u2)
        if (iters > 3) ACC8(u3)
        if (iters > 4) {
            ISS(h2q, 4, u0)
            if (iters > 5) ISS(h2q, 5, u1)
            if (iters > 6) ISS(h2q, 6, u2)
            if (iters > 7) ISS(h2q, 7, u3)
            ACC8(u0)
            if (iters > 5) ACC8(u1)
            if (iters > 6) ACC8(u2)
            if (iters > 7) ACC8(u3)
        }
    }
    RED2(a0) RED2(a1) RED2(a2) RED2(a3) RED2(a4) RED2(a5) RED2(a6) RED2(a7)
    // all 32 lanes of each half now hold their node's totals
    bool act = (c < 5) && ok;
    float v0=-1e30f,v1=-1e30f,v2=-1e30f,v3=-1e30f,v4=-1e30f,v5=-1e30f,v6=-1e30f,v7=-1e30f;
    if (act) {
        float dv = dinv[nd];
        u4v us = h2q[(size_t)nd * 8 + c];   // self-loop
        v0 = fmaf(a0 + bf_lo(us.x), dv, b2[8*c+0]);
        v1 = fmaf(a1 + bf_hi(us.x), dv, b2[8*c+1]);
        v2 = fmaf(a2 + bf_lo(us.y), dv, b2[8*c+2]);
        v3 = fmaf(a3 + bf_hi(us.y), dv, b2[8*c+3]);
        v4 = fmaf(a4 + bf_lo(us.z), dv, b2[8*c+4]);
        v5 = fmaf(a5 + bf_hi(us.z), dv, b2[8*c+5]);
        v6 = fmaf(a6 + bf_lo(us.w), dv, b2[8*c+6]);
        v7 = fmaf(a7 + bf_hi(us.w), dv, b2[8*c+7]);
    }
    float mx = fmaxf(fmaxf(fmaxf(v0, v1), fmaxf(v2, v3)),
                     fmaxf(fmaxf(v4, v5), fmaxf(v6, v7)));
#pragma unroll
    for (int off = 1; off <= 4; off <<= 1) mx = fmaxf(mx, __shfl_xor(mx, off));
    float ex = 0.f;
    if (act)
        ex = expf(v0-mx)+expf(v1-mx)+expf(v2-mx)+expf(v3-mx)
           + expf(v4-mx)+expf(v5-mx)+expf(v6-mx)+expf(v7-mx);
#pragma unroll
    for (int off = 1; off <= 4; off <<= 1) ex += __shfl_xor(ex, off);
    float lg = logf(ex);
    if (act && gg == 0) {
        float4 o0, o1;
        o0.x = v0-mx-lg; o0.y = v1-mx-lg; o0.z = v2-mx-lg; o0.w = v3-mx-lg;
        o1.x = v4-mx-lg; o1.y = v5-mx-lg; o1.z = v6-mx-lg; o1.w = v7-mx-lg;
        float4* dst = reinterpret_cast<float4*>(&out[(size_t)nd * F_OUT + 8 * c]);
        dst[0] = o0;
        dst[1] = o1;
    }
}

extern "C" void kernel_launch(void* const* d_in, const int* in_sizes, int n_in,
                              void* d_out, int out_size, void* d_ws, size_t ws_size,
                              hipStream_t stream) {
    const float* x  = (const float*)d_in[0];
    const int*   ei = (const int*)d_in[1];
    const float* W1 = (const float*)d_in[2];
    const float* b1 = (const float*)d_in[3];
    const float* W2 = (const float*)d_in[4];
    const float* b2 = (const float*)d_in[5];
    float* out = (float*)d_out;

    const int n = in_sizes[0] / F_IN;
    const int E = in_sizes[1] / 2;
    const int* row = ei;
    const int* col = ei + E;
    const int nb = (n + BSZ - 1) / BSZ;   // 391 for n=100K

    char* p = (char*)d_ws;
    float*    dinv = (float*)p;     p += (size_t)n * 4;
    int*      beg  = (int*)p;       p += (size_t)n * 4;
    int*      deg  = (int*)p;       p += (size_t)n * 4;
    int*      gcur = (int*)p;       p += NB_MAX * 4;
    unsigned* w1f  = (unsigned*)p;  p += 16 * 64 * 4 * 4;
    unsigned* bbuf = (unsigned*)p;  p += (size_t)nb * CAP * 4;
    int*      srow = (int*)p;       p += (size_t)nb * CAP * 4;
    unsigned* h1b  = (unsigned*)p;  p += (size_t)(n + 1) * 32 * 4;   // 128B rows (+dummy)
    unsigned* h2b  = (unsigned*)p;  p += (size_t)(n + 1) * 32 * 4;   // 128B-padded rows (+dummy)

    k_w1frag<<<4, 256, 0, stream>>>(W1, w1f, h1b, h2b, gcur, n);
    k_partition<<<640, 256, 0, stream>>>(row, col, E, nb, gcur, bbuf);
    k_csr<<<nb, 1024, 0, stream>>>(bbuf, gcur, beg, deg, dinv, srow, n);
    k_lin1<<<(n + 63) / 64, 256, 0, stream>>>(x, w1f, dinv, h1b, n);
    k_agg1<<<(n + 7) / 8, 256, 0, stream>>>((const u4v*)h1b, beg, deg, srow, dinv, b1, W2, h2b, n);
    k_agg2<<<(n + 7) / 8, 256, 0, stream>>>((const u4v*)h2b, beg, deg, srow, dinv, b2, out, n);
}

// Round 18
// 253.759 us; speedup vs baseline: 1.8009x; 1.7449x over previous
//
#include <hip/hip_runtime.h>

#define F_IN  128
#define F_HID 64
#define F_OUT 40
#define BSZ   256          // nodes per bucket
#define BSH   8            // log2(BSZ)
#define NB_MAX 512
#define CAP   12288        // bucket region capacity (mean 8163, sigma ~90)

typedef __attribute__((ext_vector_type(8))) short v8s;      // 8 bf16 (4 VGPRs)
typedef __attribute__((ext_vector_type(4))) float v4f;      // 4 fp32 acc
typedef __attribute__((ext_vector_type(4))) unsigned u4v;   // native uint4

// pack two floats as bf16 pair (round-to-nearest-even): low16 = a, high16 = b
static __device__ __forceinline__ unsigned pack_bf16(float a, float b) {
    unsigned ua = __float_as_uint(a);
    unsigned ub = __float_as_uint(b);
    ua = (ua + 0x7fffu + ((ua >> 16) & 1u)) >> 16;
    ub = (ub + 0x7fffu + ((ub >> 16) & 1u)) & 0xffff0000u;
    return ua | ub;
}
static __device__ __forceinline__ float bf_lo(unsigned u) { return __uint_as_float(u << 16); }
static __device__ __forceinline__ float bf_hi(unsigned u) { return __uint_as_float(u & 0xffff0000u); }

// ---------------- partition edges into destination buckets ----------------
__global__ void k_partition(const int* __restrict__ row, const int* __restrict__ col,
                            int E, int nb, int* __restrict__ gcur,
                            unsigned* __restrict__ bbuf) {
    __shared__ int hist[NB_MAX];
    __shared__ int cur[NB_MAX];
    int t = threadIdx.x;
    for (int i = t; i < nb; i += 256) hist[i] = 0;
    __syncthreads();
    int chunk = (E + gridDim.x - 1) / gridDim.x;
    int e0 = blockIdx.x * chunk;
    int e1 = min(E, e0 + chunk);
    for (int e = e0 + t; e < e1; e += 256)
        atomicAdd(&hist[col[e] >> BSH], 1);
    __syncthreads();
    for (int i = t; i < nb; i += 256)
        cur[i] = i * CAP + atomicAdd(&gcur[i], hist[i]);
    __syncthreads();
    for (int e = e0 + t; e < e1; e += 256) {
        int c = col[e];
        int b = c >> BSH;
        int pos = atomicAdd(&cur[b], 1);
        if (pos < (b + 1) * CAP)
            bbuf[pos] = ((unsigned)row[e] << BSH) | (unsigned)(c & (BSZ - 1));
    }
}

// ---------------- per-bucket counting sort -> bucket-relative CSR ----------------
__global__ void __launch_bounds__(1024)
k_csr(const unsigned* __restrict__ bbuf, const int* __restrict__ gcur,
      int* __restrict__ beg, int* __restrict__ deg, float* __restrict__ dinv,
      int* __restrict__ srow, int n) {
    __shared__ unsigned pay[CAP];   // 48 KB
    __shared__ int cnt[BSZ];
    __shared__ int cur[BSZ];
    int b = blockIdx.x, t = threadIdx.x;
    int nE = min(gcur[b], CAP);
    int base = b * CAP;
    if (t < BSZ) cnt[t] = 0;
    __syncthreads();
    for (int i = t; i < nE; i += 1024) {
        unsigned u = bbuf[base + i];
        pay[i] = u;
        atomicAdd(&cnt[u & (BSZ - 1)], 1);
    }
    __syncthreads();
    if (t < BSZ) cur[t] = cnt[t];
    __syncthreads();
    for (int off = 1; off < BSZ; off <<= 1) {
        int add = (t < BSZ && t >= off) ? cur[t - off] : 0;
        __syncthreads();
        if (t < BSZ) cur[t] += add;
        __syncthreads();
    }
    int node0 = b * BSZ;
    if (t < BSZ) {
        int ex = cur[t] - cnt[t];
        int node = node0 + t;
        if (node < n) {
            beg[node] = base + ex;
            deg[node] = cnt[t];
            dinv[node] = rsqrtf((float)cnt[t] + 1.0f);
        }
        cur[t] = ex;
    }
    __syncthreads();
    for (int i = t; i < nE; i += 1024) {
        unsigned u = pay[i];
        int pos = atomicAdd(&cur[u & (BSZ - 1)], 1);
        srow[base + pos] = (int)(u >> BSH);
    }
}

// ---------------- W1 fragments + zero dummy rows + zero gcur (runs first) ----------------
__global__ void k_w1frag(const float* __restrict__ W1, unsigned* __restrict__ w1f,
                         unsigned* __restrict__ h1b, unsigned* __restrict__ h2b,
                         int* __restrict__ gcur, int n) {
    int gid = blockIdx.x * 256 + threadIdx.x;
    if (gid < 32) h1b[(size_t)n * 32 + gid] = 0u;        // dummy zero row (layer 1)
    if (gid < 32) h2b[(size_t)n * 32 + gid] = 0u;        // dummy zero row (layer 2)
    if (gid < NB_MAX) gcur[gid] = 0;
    if (gid >= 16 * 64) return;
    int f = gid >> 6, l = gid & 63;
    int j0 = f >> 2, ks = f & 3;
    int col = 16 * j0 + (l & 15);
    int kb = ks * 32 + ((l >> 4) << 3);
#pragma unroll
    for (int d = 0; d < 4; ++d) {
        float a = W1[(kb + 2 * d) * F_HID + col];
        float b = W1[(kb + 2 * d + 1) * F_HID + col];
        w1f[(size_t)gid * 4 + d] = pack_bf16(a, b);
    }
}

// ---------------- layer 1 linear via MFMA: h1b = bf16( dinv * (x @ W1) ) ----------------
__global__ void k_lin1(const float* __restrict__ x, const unsigned* __restrict__ w1f,
                       const float* __restrict__ dinv, unsigned* __restrict__ h1b, int n) {
    int t = threadIdx.x;
    int l = t & 63, w = t >> 6;
    int node0 = blockIdx.x * 64 + w * 16;
    int arow = min(node0 + (l & 15), n - 1);   // clamped A-row (safe OOB)
    const u4v* wf4 = (const u4v*)w1f;
    v8s bf[16];
#pragma unroll
    for (int f = 0; f < 16; ++f) {
        u4v u = wf4[f * 64 + l];
        bf[f] = *(v8s*)&u;
    }
    v8s af[4];
#pragma unroll
    for (int ks = 0; ks < 4; ++ks) {
        int kb = ks * 32 + ((l >> 4) << 3);
        const float4* xp = (const float4*)&x[(size_t)arow * F_IN + kb];
        float4 x0 = xp[0], x1 = xp[1];
        u4v uu = { pack_bf16(x0.x, x0.y), pack_bf16(x0.z, x0.w),
                   pack_bf16(x1.x, x1.y), pack_bf16(x1.z, x1.w) };
        af[ks] = *(v8s*)&uu;
    }
#pragma unroll
    for (int j0 = 0; j0 < 4; ++j0) {
        v4f acc = {0.f, 0.f, 0.f, 0.f};
#pragma unroll
        for (int ks = 0; ks < 4; ++ks)
            acc = __builtin_amdgcn_mfma_f32_16x16x32_bf16(af[ks], bf[j0 * 4 + ks], acc, 0, 0, 0);
#pragma unroll
        for (int i = 0; i < 4; ++i) {
            int node = node0 + ((l >> 4) << 2) + i;
            float s = acc[i] * dinv[min(node, n - 1)];
            float pr = __shfl_xor(s, 1);
            if (!(l & 1) && node < n)
                h1b[(size_t)node * 32 + 8 * j0 + ((l & 15) >> 1)] = pack_bf16(s, pr);
        }
    }
}

// gathers: out-of-range lanes carry the dummy row index (n), whose row is zero.
#define ISSUE1(i, u) { int rr = __shfl(r, (i) * 8 + g); u = h1q[(size_t)rr * 8 + c]; }
#define ISSUE2(i, u) { int rr = __shfl(r, (i) * 8 + g); u = h2q[(size_t)rr * 8 + c]; }
#define ACCUM(u) { a0 += bf_lo(u.x); a1 += bf_hi(u.x); \
                   a2 += bf_lo(u.y); a3 += bf_hi(u.y); \
                   a4 += bf_lo(u.z); a5 += bf_hi(u.z); \
                   a6 += bf_lo(u.w); a7 += bf_hi(u.w); }

// ---------------- layer-1 aggregation (pipelined uint4 gathers) + relu + fused W2 GEMM ----------------
__global__ void k_agg1(const u4v* __restrict__ h1q, const int* __restrict__ beg,
                       const int* __restrict__ deg, const int* __restrict__ srow,
                       const float* __restrict__ dinv, const float* __restrict__ b1,
                       const float* __restrict__ W2, unsigned* __restrict__ h2b, int n) {
    __shared__ float W2s[F_HID * F_OUT];  // 10 KB
    __shared__ float b1s[F_HID];
    __shared__ float zrow[4][F_HID];
    int t = threadIdx.x;
    for (int i = t; i < F_HID * F_OUT; i += 256) W2s[i] = W2[i];
    if (t < F_HID) b1s[t] = b1[t];
    __syncthreads();
    int lane = t & 63, w = t >> 6;
    int g = lane >> 3, c = lane & 7;
    int node = blockIdx.x * 4 + w;
    if (node >= n) return;
    int bg = beg[node], cnt = deg[node];
    float a0=0.f,a1=0.f,a2=0.f,a3=0.f,a4=0.f,a5=0.f,a6=0.f,a7=0.f;
    for (int e0 = 0; e0 < cnt; e0 += 64) {
        int m = min(64, cnt - e0);
        int r = (lane < m) ? srow[bg + e0 + lane] : n;   // pad lanes -> dummy zero row
        int iters = (m + 7) >> 3;
        u4v u0, u1, u2, u3;
        ISSUE1(0, u0) ISSUE1(1, u1) ISSUE1(2, u2) ISSUE1(3, u3)
        ACCUM(u0) ACCUM(u1) ACCUM(u2) ACCUM(u3)
        if (iters > 4) {
            ISSUE1(4, u0)
            if (iters > 5) ISSUE1(5, u1)
            if (iters > 6) ISSUE1(6, u2)
            if (iters > 7) ISSUE1(7, u3)
            ACCUM(u0)
            if (iters > 5) ACCUM(u1)
            if (iters > 6) ACCUM(u2)
            if (iters > 7) ACCUM(u3)
        }
    }
#pragma unroll
    for (int off = 8; off <= 32; off <<= 1) {
        a0 += __shfl_xor(a0, off); a1 += __shfl_xor(a1, off);
        a2 += __shfl_xor(a2, off); a3 += __shfl_xor(a3, off);
        a4 += __shfl_xor(a4, off); a5 += __shfl_xor(a5, off);
        a6 += __shfl_xor(a6, off); a7 += __shfl_xor(a7, off);
    }
    float dv = dinv[node];
    if (g == 0) {
        u4v us = h1q[(size_t)node * 8 + c];   // self-loop (already dinv-scaled)
        a0 += bf_lo(us.x); a1 += bf_hi(us.x);
        a2 += bf_lo(us.y); a3 += bf_hi(us.y);
        a4 += bf_lo(us.z); a5 += bf_hi(us.z);
        a6 += bf_lo(us.w); a7 += bf_hi(us.w);
        float z;
        z = fmaf(a0, dv, b1s[8*c+0]); zrow[w][8*c+0] = z > 0.f ? z : 0.f;
        z = fmaf(a1, dv, b1s[8*c+1]); zrow[w][8*c+1] = z > 0.f ? z : 0.f;
        z = fmaf(a2, dv, b1s[8*c+2]); zrow[w][8*c+2] = z > 0.f ? z : 0.f;
        z = fmaf(a3, dv, b1s[8*c+3]); zrow[w][8*c+3] = z > 0.f ? z : 0.f;
        z = fmaf(a4, dv, b1s[8*c+4]); zrow[w][8*c+4] = z > 0.f ? z : 0.f;
        z = fmaf(a5, dv, b1s[8*c+5]); zrow[w][8*c+5] = z > 0.f ? z : 0.f;
        z = fmaf(a6, dv, b1s[8*c+6]); zrow[w][8*c+6] = z > 0.f ? z : 0.f;
        z = fmaf(a7, dv, b1s[8*c+7]); zrow[w][8*c+7] = z > 0.f ? z : 0.f;
    }
    // same-wave DS write->read (in-order DS pipe)
    float s = 0.f;
    if (lane < F_OUT) {
#pragma unroll
        for (int k = 0; k < F_HID; ++k)
            s = fmaf(zrow[w][k], W2s[k * F_OUT + lane], s);
        s *= dv;
    }
    float partner = __shfl_xor(s, 1);
    if (lane < F_OUT && (lane & 1) == 0)
        h2b[(size_t)node * 32 + (lane >> 1)] = pack_bf16(s, partner);   // 128B-padded rows
}

// ---------------- layer-2 aggregation (128B-padded rows) + bias + fused log_softmax ----------------
__global__ void k_agg2(const u4v* __restrict__ h2q, const int* __restrict__ beg,
                       const int* __restrict__ deg, const int* __restrict__ srow,
                       const float* __restrict__ dinv, const float* __restrict__ b2,
                       float* __restrict__ out, int n) {
    int t = threadIdx.x, lane = t & 63, w = t >> 6;
    int g = lane >> 3, c = lane & 7;
    bool act = c < 5;      // pad dwords (c>=5) accumulate junk that is never read
    int node = blockIdx.x * 4 + w;
    if (node >= n) return;
    int bg = beg[node], cnt = deg[node];
    float a0=0.f,a1=0.f,a2=0.f,a3=0.f,a4=0.f,a5=0.f,a6=0.f,a7=0.f;
    for (int e0 = 0; e0 < cnt; e0 += 64) {
        int m = min(64, cnt - e0);
        int r = (lane < m) ? srow[bg + e0 + lane] : n;   // dummy zero row
        int iters = (m + 7) >> 3;
        u4v u0, u1, u2, u3;
        ISSUE2(0, u0) ISSUE2(1, u1) ISSUE2(2, u2) ISSUE2(3, u3)
        ACCUM(u0) ACCUM(u1) ACCUM(u2) ACCUM(u3)
        if (iters > 4) {
            ISSUE2(4, u0)
            if (iters > 5) ISSUE2(5, u1)
            if (iters > 6) ISSUE2(6, u2)
            if (iters > 7) ISSUE2(7, u3)
            ACCUM(u0)
            if (iters > 5) ACCUM(u1)
            if (iters > 6) ACCUM(u2)
            if (iters > 7) ACCUM(u3)
        }
    }
#pragma unroll
    for (int off = 8; off <= 32; off <<= 1) {
        a0 += __shfl_xor(a0, off); a1 += __shfl_xor(a1, off);
        a2 += __shfl_xor(a2, off); a3 += __shfl_xor(a3, off);
        a4 += __shfl_xor(a4, off); a5 += __shfl_xor(a5, off);
        a6 += __shfl_xor(a6, off); a7 += __shfl_xor(a7, off);
    }
    float dv = dinv[node];
    float v0=-1e30f,v1=-1e30f,v2=-1e30f,v3=-1e30f,v4=-1e30f,v5=-1e30f,v6=-1e30f,v7=-1e30f;
    if (act) {
        u4v us = h2q[(size_t)node * 8 + c];   // self-loop
        v0 = fmaf(a0 + bf_lo(us.x), dv, b2[8*c+0]);
        v1 = fmaf(a1 + bf_hi(us.x), dv, b2[8*c+1]);
        v2 = fmaf(a2 + bf_lo(us.y), dv, b2[8*c+2]);
        v3 = fmaf(a3 + bf_hi(us.y), dv, b2[8*c+3]);
        v4 = fmaf(a4 + bf_lo(us.z), dv, b2[8*c+4]);
        v5 = fmaf(a5 + bf_hi(us.z), dv, b2[8*c+5]);
        v6 = fmaf(a6 + bf_lo(us.w), dv, b2[8*c+6]);
        v7 = fmaf(a7 + bf_hi(us.w), dv, b2[8*c+7]);
    }
    float mx = fmaxf(fmaxf(fmaxf(v0, v1), fmaxf(v2, v3)),
                     fmaxf(fmaxf(v4, v5), fmaxf(v6, v7)));
#pragma unroll
    for (int off = 1; off <= 4; off <<= 1) mx = fmaxf(mx, __shfl_xor(mx, off));
    float ex = 0.f;
    if (act)
        ex = expf(v0-mx)+expf(v1-mx)+expf(v2-mx)+expf(v3-mx)
           + expf(v4-mx)+expf(v5-mx)+expf(v6-mx)+expf(v7-mx);
#pragma unroll
    for (int off = 1; off <= 4; off <<= 1) ex += __shfl_xor(ex, off);
    float lg = logf(ex);
    if (g == 0 && act) {
        float4 o0, o1;
        o0.x = v0-mx-lg; o0.y = v1-mx-lg; o0.z = v2-mx-lg; o0.w = v3-mx-lg;
        o1.x = v4-mx-lg; o1.y = v5-mx-lg; o1.z = v6-mx-lg; o1.w = v7-mx-lg;
        float4* dst = reinterpret_cast<float4*>(&out[(size_t)node * F_OUT + 8 * c]);
        dst[0] = o0;
        dst[1] = o1;
    }
}

extern "C" void kernel_launch(void* const* d_in, const int* in_sizes, int n_in,
                              void* d_out, int out_size, void* d_ws, size_t ws_size,
                              hipStream_t stream) {
    const float* x  = (const float*)d_in[0];
    const int*   ei = (const int*)d_in[1];
    const float* W1 = (const float*)d_in[2];
    const float* b1 = (const float*)d_in[3];
    const float* W2 = (const float*)d_in[4];
    const float* b2 = (const float*)d_in[5];
    float* out = (float*)d_out;

    const int n = in_sizes[0] / F_IN;
    const int E = in_sizes[1] / 2;
    const int* row = ei;
    const int* col = ei + E;
    const int nb = (n + BSZ - 1) / BSZ;   // 391 for n=100K

    char* p = (char*)d_ws;
    float*    dinv = (float*)p;     p += (size_t)n * 4;
    int*      beg  = (int*)p;       p += (size_t)n * 4;
    int*      deg  = (int*)p;       p += (size_t)n * 4;
    int*      gcur = (int*)p;       p += NB_MAX * 4;
    unsigned* w1f  = (unsigned*)p;  p += 16 * 64 * 4 * 4;
    unsigned* bbuf = (unsigned*)p;  p += (size_t)nb * CAP * 4;
    int*      srow = (int*)p;       p += (size_t)nb * CAP * 4;
    unsigned* h1b  = (unsigned*)p;  p += (size_t)(n + 1) * 32 * 4;   // 128B rows (+dummy)
    unsigned* h2b  = (unsigned*)p;  p += (size_t)(n + 1) * 32 * 4;   // 128B-padded rows (+dummy)

    k_w1frag<<<4, 256, 0, stream>>>(W1, w1f, h1b, h2b, gcur, n);
    k_partition<<<640, 256, 0, stream>>>(row, col, E, nb, gcur, bbuf);
    k_csr<<<nb, 1024, 0, stream>>>(bbuf, gcur, beg, deg, dinv, srow, n);
    k_lin1<<<(n + 63) / 64, 256, 0, stream>>>(x, w1f, dinv, h1b, n);
    k_agg1<<<(n + 3) / 4, 256, 0, stream>>>((const u4v*)h1b, beg, deg, srow, dinv, b1, W2, h2b, n);
    k_agg2<<<(n + 3) / 4, 256, 0, stream>>>((const u4v*)h2b, beg, deg, srow, dinv, b2, out, n);
}